// Round 4
// baseline (1491.989 us; speedup 1.0000x reference)
//
#include <hip/hip_runtime.h>

typedef float f32x4 __attribute__((ext_vector_type(4)));
typedef __bf16 bf16x8 __attribute__((ext_vector_type(8)));
typedef unsigned short u16x8 __attribute__((ext_vector_type(8)));
typedef unsigned short u16x4 __attribute__((ext_vector_type(4)));

static __device__ __forceinline__ unsigned short f2bf(float f) {
  unsigned int x = __builtin_bit_cast(unsigned int, f);
  x += 0x7FFFu + ((x >> 16) & 1u);
  return (unsigned short)(x >> 16);
}
static __device__ __forceinline__ float bf2f(unsigned short h) {
  unsigned int x = ((unsigned int)h) << 16;
  return __builtin_bit_cast(float, x);
}

static __device__ __forceinline__ void gload_lds16(const unsigned short* g,
                                                   unsigned short* l) {
  __builtin_amdgcn_global_load_lds(
      (const __attribute__((address_space(1))) void*)g,
      (__attribute__((address_space(3))) void*)l, 16, 0, 0);
}

// ---------------- f32 -> bf16 elementwise (vectorized) ----------------
__global__ __launch_bounds__(256) void k_f32_to_bf16(
    const float* __restrict__ in, unsigned short* __restrict__ out, int n4) {
  int i = blockIdx.x * 256 + threadIdx.x;
  if (i >= n4) return;
  float4 v = reinterpret_cast<const float4*>(in)[i];
  u16x4 o = {f2bf(v.x), f2bf(v.y), f2bf(v.z), f2bf(v.w)};
  reinterpret_cast<u16x4*>(out)[i] = o;
}

// ---------------- transpose + convert: out[z][n][k] = in[z][k][n] ----------------
__global__ __launch_bounds__(256) void k_transpose_bf16(
    const float* __restrict__ in, unsigned short* __restrict__ out, int D) {
  __shared__ float tile[32][33];
  const size_t msz = (size_t)D * D;
  const float* A = in + msz * blockIdx.z;
  unsigned short* O = out + msz * blockIdx.z;
  int nt = blockIdx.x * 32, kt = blockIdx.y * 32;
  int tx = threadIdx.x, ty = threadIdx.y;
#pragma unroll
  for (int i = 0; i < 4; ++i)
    tile[ty + i * 8][tx] = A[(size_t)(kt + ty + i * 8) * D + nt + tx];
  __syncthreads();
#pragma unroll
  for (int i = 0; i < 4; ++i)
    O[(size_t)(nt + ty + i * 8) * D + kt + tx] = f2bf(tile[tx][ty + i * 8]);
}

// ---------------- edge sort by (rel, dst): histogram / scan / bucket ----------------
__global__ __launch_bounds__(256) void k_hist(const int* __restrict__ dst,
                                              const int* __restrict__ rel,
                                              int* __restrict__ cnt, int E, int N) {
  int e = blockIdx.x * 256 + threadIdx.x;
  if (e < E) atomicAdd(&cnt[rel[e] * N + dst[e]], 1);
}

// block-parallel exclusive scan (1 block x 1024 threads, chunk per thread)
__global__ __launch_bounds__(1024) void k_scan(const int* __restrict__ cnt,
                                               int* __restrict__ off, int N) {
  __shared__ int wpre[16];
  int tid = threadIdx.x, lane = tid & 63, w = tid >> 6;
  const int CH = (N + 1023) >> 10;
  int base = tid * CH;
  int s = 0;
  for (int j = 0; j < CH; ++j) {
    int i = base + j;
    s += (i < N) ? cnt[i] : 0;
  }
  int inc = s;
#pragma unroll
  for (int d = 1; d < 64; d <<= 1) {
    int t2 = __shfl_up(inc, d, 64);
    if (lane >= d) inc += t2;
  }
  if (lane == 63) wpre[w] = inc;
  __syncthreads();
  if (w == 0) {
    int v = (lane < 16) ? wpre[lane] : 0;
    int p = v;
#pragma unroll
    for (int d = 1; d < 16; d <<= 1) {
      int t2 = __shfl_up(p, d, 64);
      if (lane >= d) p += t2;
    }
    if (lane < 16) wpre[lane] = p - v;  // exclusive wave base
  }
  __syncthreads();
  int run = wpre[w] + inc - s;
  for (int j = 0; j < CH; ++j) {
    int i = base + j;
    if (i < N) {
      off[i] = run;
      run += cnt[i];
    }
  }
  if (tid == 1023) off[N] = run;
}

__global__ __launch_bounds__(256) void k_bucket(
    const int* __restrict__ src, const int* __restrict__ dst,
    const int* __restrict__ rel, const float* __restrict__ norm,
    const int* __restrict__ off, int* __restrict__ fill,
    int* __restrict__ spack, float* __restrict__ snorm, int E, int N) {
  int e = blockIdx.x * 256 + threadIdx.x;
  if (e >= E) return;
  int key = rel[e] * N + dst[e];
  int slot = off[key] + atomicAdd(&fill[key], 1);
  spack[slot] = src[e];
  snorm[slot] = norm[e];
}

// ---------------- gather-aggregate: agg[v] (+)= sum over in-edges of norm*HW[src,rel] ----------------
// edges sorted by (rel,dst); wave per dst node; lane owns 12 contiguous cols
__global__ __launch_bounds__(256) void k_gather(
    const unsigned short* __restrict__ HW, const int* __restrict__ off,
    const int* __restrict__ spack, const float* __restrict__ snorm,
    float* __restrict__ agg, int N, int r0, int r1, int ldHW, int accum) {
  int v = (blockIdx.x * 256 + threadIdx.x) >> 6;
  if (v >= N) return;
  int lane = threadIdx.x & 63;
  float a[12];
#pragma unroll
  for (int j = 0; j < 12; ++j) a[j] = 0.f;
  for (int r = r0; r < r1; ++r) {
    int beg = off[r * N + v], end = off[r * N + v + 1];
    const unsigned short* rbase = HW + (size_t)(r - r0) * 768 + lane * 12;
    for (int p = beg; p < end; ++p) {
      int s = spack[p];
      float nm = snorm[p];
      const unsigned short* row = rbase + (size_t)s * ldHW;
#pragma unroll
      for (int u = 0; u < 3; ++u) {
        u16x4 vv = *reinterpret_cast<const u16x4*>(row + u * 4);
#pragma unroll
        for (int j = 0; j < 4; ++j) a[u * 4 + j] += nm * bf2f(vv[j]);
      }
    }
  }
  float* orow = agg + (size_t)v * 768 + lane * 12;
  if (accum) {
#pragma unroll
    for (int u = 0; u < 3; ++u) {
      float4 o = reinterpret_cast<float4*>(orow)[u];
      o.x += a[u * 4 + 0]; o.y += a[u * 4 + 1];
      o.z += a[u * 4 + 2]; o.w += a[u * 4 + 3];
      reinterpret_cast<float4*>(orow)[u] = o;
    }
  } else {
#pragma unroll
    for (int u = 0; u < 3; ++u) {
      float4 o = {a[u * 4 + 0], a[u * 4 + 1], a[u * 4 + 2], a[u * 4 + 3]};
      reinterpret_cast<float4*>(orow)[u] = o;
    }
  }
}

// ---------------- bf16 GEMM: C[M,N] = A[M,K] @ B^T[N,K], f32 accum ----------------
// 256x256 tile, BK=64, 8 waves. 8-phase-style schedule: per K-tile 4 phases,
// phase (ma,nb) computes C-quadrant [ma*128,+128)x[nb*128,+128) (waves 2x4 ->
// 64x32 each: 16 MFMA, 12 ds_read_b128). Double-buffered LDS in 4 half-tiles;
// stage stream per tile t: [t+1.Ahi, t+1.Blo, t+2.Alo, t+2.Bhi] -- each stage
// targets a region past its last read (phase order (0,1),(0,0),(1,1),(1,0)
// frees A-lo after ph2, B-hi after ph3; 2 barriers/phase enforce it).
// One counted s_waitcnt vmcnt(4) per K-tile (T4); setprio around MFMA (T5);
// 16B-chunk XOR swizzle chunk^=(row&7) on pre-swizzled global source (T2).
// A and B rows must be padded to multiples of 256.
#define STAGE_A(BUF, HALF, TT)                                                   \
  do {                                                                           \
    const unsigned short* _s =                                                   \
        A + (size_t)(m0 + (HALF) * 128 + srow) * K + (size_t)(TT) * 64 + gcol;   \
    gload_lds16(_s, &As[BUF][HALF][w << 3][0]);                                  \
    gload_lds16(_s + (size_t)64 * K, &As[BUF][HALF][64 + (w << 3)][0]);          \
  } while (0)
#define STAGE_B(BUF, HALF, TT)                                                   \
  do {                                                                           \
    const unsigned short* _s =                                                   \
        B + (size_t)(n0 + (HALF) * 128 + srow) * K + (size_t)(TT) * 64 + gcol;   \
    gload_lds16(_s, &Bs[BUF][HALF][w << 3][0]);                                  \
    gload_lds16(_s + (size_t)64 * K, &Bs[BUF][HALF][64 + (w << 3)][0]);          \
  } while (0)
#define PHASE(MA, NB, ...)                                                       \
  do {                                                                           \
    bf16x8 af[4][2], bv[2][2];                                                   \
    _Pragma("unroll") for (int i = 0; i < 4; ++i)                                \
        _Pragma("unroll") for (int kk = 0; kk < 2; ++kk)                         \
            af[i][kk] = *reinterpret_cast<const bf16x8*>(                        \
                &As[buf][MA][wr * 64 + i * 16 + lr]                              \
                   [((lg + 4 * kk) ^ (lr & 7)) * 8]);                            \
    _Pragma("unroll") for (int j = 0; j < 2; ++j)                                \
        _Pragma("unroll") for (int kk = 0; kk < 2; ++kk)                         \
            bv[j][kk] = *reinterpret_cast<const bf16x8*>(                        \
                &Bs[buf][NB][wc * 32 + j * 16 + lr]                              \
                   [((lg + 4 * kk) ^ (lr & 7)) * 8]);                            \
    __VA_ARGS__;                                                                 \
    asm volatile("" ::: "memory");                                               \
    __builtin_amdgcn_s_barrier();                                                \
    asm volatile("" ::: "memory");                                               \
    __builtin_amdgcn_s_setprio(1);                                               \
    _Pragma("unroll") for (int i = 0; i < 4; ++i)                                \
        _Pragma("unroll") for (int j = 0; j < 2; ++j)                            \
            _Pragma("unroll") for (int kk = 0; kk < 2; ++kk)                     \
                acc[MA][NB][i][j] = __builtin_amdgcn_mfma_f32_16x16x32_bf16(     \
                    af[i][kk], bv[j][kk], acc[MA][NB][i][j], 0, 0, 0);           \
    __builtin_amdgcn_s_setprio(0);                                               \
    asm volatile("" ::: "memory");                                               \
    __builtin_amdgcn_s_barrier();                                                \
    asm volatile("" ::: "memory");                                               \
  } while (0)

template <int EPI>
__global__ __launch_bounds__(512, 2) void k_gemm_tn(
    const unsigned short* __restrict__ A, const unsigned short* __restrict__ B,
    unsigned short* __restrict__ C, const float* __restrict__ C0,
    int M, int N, int K, int MT, int NT) {
  __shared__ unsigned short As[2][2][128][64];  // [buf][half][row][k]
  __shared__ unsigned short Bs[2][2][128][64];
  const int tid = threadIdx.x;
  const int lane = tid & 63;
  const int w = tid >> 6;  // 0..7
  const int wr = w >> 2;   // 0..1 (M within quadrant)
  const int wc = w & 3;    // 0..3 (N within quadrant)
  const int lr = lane & 15, lg = lane >> 4;

  // supergroup-of-8 M-tiles block swizzle for B-panel L2 reuse
  int bid = blockIdx.x;
  const int per = 8 * NT;
  int grp = bid / per, rem = bid % per;
  int mstart = grp * 8;
  int gsz = MT - mstart; if (gsz > 8) gsz = 8;
  const int mt = mstart + rem % gsz;
  const int ntile = rem / gsz;
  const int m0 = mt * 256, n0 = ntile * 256;

  // staging map: thread -> row tid>>3 (0..63) (+64 for 2nd issue), 16B chunk tid&7,
  // global chunk pre-swizzled so LDS[row][c] = global[row][c ^ (row&7)]
  const int srow = tid >> 3;
  const int gcol = (((tid & 7) ^ (tid >> 3)) & 7) * 8;

  f32x4 acc[2][2][4][2] = {};  // [ma][nb][i][j]
  const int nk = K >> 6;

  // prologue stream: t0.Alo, t0.Bhi, t0.Ahi, t0.Blo, t1.Alo, t1.Bhi
  STAGE_A(0, 0, 0);
  STAGE_B(0, 1, 0);
  STAGE_A(0, 1, 0);
  STAGE_B(0, 0, 0);
  if (nk > 1) {
    STAGE_A(1, 0, 1);
    STAGE_B(1, 1, 1);
  }

  for (int t = 0; t < nk; ++t) {
    const int buf = t & 1;
    if (t + 1 < nk)
      asm volatile("s_waitcnt vmcnt(4)" ::: "memory");  // keep t+1 halves in flight
    else
      asm volatile("s_waitcnt vmcnt(0)" ::: "memory");
    __builtin_amdgcn_s_barrier();  // tile t fully resident for all waves
    asm volatile("" ::: "memory");
    PHASE(0, 1, if (t + 1 < nk) STAGE_A(buf ^ 1, 1, t + 1));
    PHASE(0, 0, if (t + 1 < nk) STAGE_B(buf ^ 1, 0, t + 1));
    PHASE(1, 1, if (t + 2 < nk) STAGE_A(buf, 0, t + 2));
    PHASE(1, 0, if (t + 2 < nk) STAGE_B(buf, 1, t + 2));
  }

#pragma unroll
  for (int ma = 0; ma < 2; ++ma)
#pragma unroll
    for (int i = 0; i < 4; ++i)
#pragma unroll
      for (int q = 0; q < 4; ++q) {
        int r = m0 + ma * 128 + wr * 64 + i * 16 + lg * 4 + q;
        if (r >= M) continue;
#pragma unroll
        for (int nb = 0; nb < 2; ++nb)
#pragma unroll
          for (int j = 0; j < 2; ++j) {
            int cn = n0 + nb * 128 + wc * 32 + j * 16 + lr;
            float v = acc[ma][nb][i][j][q];
            if (EPI) {
              v += C0[(size_t)r * N + cn];
              v = v > 0.f ? v : 0.f;
            }
            C[(size_t)r * N + cn] = f2bf(v);
          }
      }
}

// ---------------- DistMult score: out[t] = dot(SW[es, er], emb[eo]) ----------------
__global__ __launch_bounds__(256) void k_score(
    const unsigned short* __restrict__ SW, const unsigned short* __restrict__ emb,
    const int* __restrict__ ps, const int* __restrict__ pr, const int* __restrict__ pd,
    const int* __restrict__ ns, const int* __restrict__ nr, const int* __restrict__ nd,
    float* __restrict__ out, int T, int r0, int r1, int ldSW) {
  int t = (blockIdx.x * 256 + threadIdx.x) >> 6;
  if (t >= 2 * T) return;
  int s, r, o;
  if (t < T) { s = ps[t]; r = pr[t]; o = pd[t]; }
  else       { s = ns[t - T]; r = nr[t - T]; o = nd[t - T]; }
  if (r < r0 || r >= r1) return;
  int lane = threadIdx.x & 63;
  const unsigned short* a = SW + (size_t)s * ldSW + (size_t)(r - r0) * 768 + lane * 12;
  const unsigned short* b = emb + (size_t)o * 768 + lane * 12;
  float acc = 0.f;
#pragma unroll
  for (int u = 0; u < 3; ++u) {
    u16x4 va = *reinterpret_cast<const u16x4*>(a + u * 4);
    u16x4 vb = *reinterpret_cast<const u16x4*>(b + u * 4);
#pragma unroll
    for (int j = 0; j < 4; ++j) acc += bf2f(va[j]) * bf2f(vb[j]);
  }
#pragma unroll
  for (int off = 32; off > 0; off >>= 1) acc += __shfl_down(acc, off, 64);
  if (lane == 0) out[t] = acc;
}

extern "C" void kernel_launch(void* const* d_in, const int* in_sizes, int n_in,
                              void* d_out, int out_size, void* d_ws, size_t ws_size,
                              hipStream_t stream) {
  const float* node_feat = (const float*)d_in[0];
  const float* edge_norm = (const float*)d_in[1];
  const float* W_rel = (const float*)d_in[2];
  const float* W_self = (const float*)d_in[3];
  const float* w_relation = (const float*)d_in[4];
  const int* src = (const int*)d_in[5];
  const int* dst = (const int*)d_in[6];
  const int* rel = (const int*)d_in[7];
  const int* pos_src = (const int*)d_in[8];
  const int* pos_rel = (const int*)d_in[9];
  const int* pos_dst = (const int*)d_in[10];
  const int* neg_src = (const int*)d_in[11];
  const int* neg_rel = (const int*)d_in[12];
  const int* neg_dst = (const int*)d_in[13];

  const int D = 768;
  const int N = in_sizes[0] / D;
  const int E = in_sizes[1];
  const int L = in_sizes[3] / (D * D);
  const int R = in_sizes[4] / (D * D);
  const int T = in_sizes[8];
  const int Mpad = (N + 255) & ~255;  // 256-row tiles, no gload_lds predication

  auto align_up = [](size_t x) { return (x + 255) & ~(size_t)255; };
  size_t sz_wt_rel = align_up((size_t)L * R * D * D * 2);
  size_t sz_wt_self = align_up((size_t)L * D * D * 2);
  size_t sz_wt_relation = align_up((size_t)R * D * D * 2);
  size_t sz_h = align_up((size_t)Mpad * D * 2);
  size_t sz_agg = align_up((size_t)N * D * 4);
  size_t sz_cntfill = align_up((size_t)2 * R * N * 4);
  size_t sz_off = align_up((size_t)(R * N + 8) * 4);
  size_t sz_spack = align_up((size_t)E * 4);
  size_t sz_snorm = align_up((size_t)E * 4);
  size_t fixed = sz_wt_rel + sz_wt_self + sz_wt_relation + 2 * sz_h + sz_agg +
                 sz_cntfill + sz_off + sz_spack + sz_snorm;
  int RG = 8;
  while (RG > 1 && fixed + (size_t)Mpad * RG * D * 2 > ws_size) RG >>= 1;

  char* wp = (char*)d_ws;
  unsigned short* wt_rel = (unsigned short*)wp; wp += sz_wt_rel;
  unsigned short* wt_self = (unsigned short*)wp; wp += sz_wt_self;
  unsigned short* wt_relation = (unsigned short*)wp; wp += sz_wt_relation;
  unsigned short* h0 = (unsigned short*)wp; wp += sz_h;
  unsigned short* h1 = (unsigned short*)wp; wp += sz_h;
  float* agg = (float*)wp; wp += sz_agg;
  int* cnt = (int*)wp; int* fill = cnt + R * N; wp += sz_cntfill;
  int* off = (int*)wp; wp += sz_off;
  int* spack = (int*)wp; wp += sz_spack;
  float* snorm = (float*)wp; wp += sz_snorm;
  unsigned short* HW = (unsigned short*)wp;

  dim3 tb32(32, 8);
  k_f32_to_bf16<<<(N * D / 4 + 255) / 256, 256, 0, stream>>>(node_feat, h0, N * D / 4);
  // zero padded tail rows of h buffers (read as GEMM A rows)
  if (Mpad > N) {
    hipMemsetAsync(h0 + (size_t)N * D, 0, (size_t)(Mpad - N) * D * 2, stream);
    hipMemsetAsync(h1 + (size_t)N * D, 0, (size_t)(Mpad - N) * D * 2, stream);
  }
  k_transpose_bf16<<<dim3(D / 32, D / 32, L * R), tb32, 0, stream>>>(W_rel, wt_rel, D);
  k_transpose_bf16<<<dim3(D / 32, D / 32, L), tb32, 0, stream>>>(W_self, wt_self, D);
  k_transpose_bf16<<<dim3(D / 32, D / 32, R), tb32, 0, stream>>>(w_relation, wt_relation, D);

  // counting sort of edges by (rel, dst)
  hipMemsetAsync(cnt, 0, (size_t)2 * R * N * 4, stream);
  k_hist<<<(E + 255) / 256, 256, 0, stream>>>(dst, rel, cnt, E, N);
  k_scan<<<1, 1024, 0, stream>>>(cnt, off, R * N);
  k_bucket<<<(E + 255) / 256, 256, 0, stream>>>(src, dst, rel, edge_norm, off, fill,
                                                spack, snorm, E, N);

  const int MT = Mpad / 256;
  unsigned short* hcur = h0;
  unsigned short* hnext = h1;
  for (int l = 0; l < L; ++l) {
    for (int g = 0; g < R; g += RG) {
      int NG = RG * D;
      int NT = NG / 256;
      k_gemm_tn<0><<<MT * NT, 512, 0, stream>>>(
          hcur, wt_rel + (size_t)(l * R + g) * D * D, HW, nullptr, N, NG, D, MT, NT);
      k_gather<<<(N + 3) / 4, 256, 0, stream>>>(HW, off, spack, snorm, agg, N,
                                                g, g + RG, NG, g > 0 ? 1 : 0);
    }
    {
      int NT = D / 256;
      k_gemm_tn<1><<<MT * NT, 512, 0, stream>>>(
          hcur, wt_self + (size_t)l * D * D, hnext, agg, N, D, D, MT, NT);
    }
    unsigned short* tmp = hcur; hcur = hnext; hnext = tmp;
  }
  // scoring: SW = emb @ w_relation[r] per group, then per-target dot
  for (int g = 0; g < R; g += RG) {
    int NG = RG * D;
    int NT = NG / 256;
    k_gemm_tn<0><<<MT * NT, 512, 0, stream>>>(
        hcur, wt_relation + (size_t)g * D * D, HW, nullptr, N, NG, D, MT, NT);
    k_score<<<(2 * T + 3) / 4, 256, 0, stream>>>(HW, hcur, pos_src, pos_rel, pos_dst,
                                                 neg_src, neg_rel, neg_dst,
                                                 (float*)d_out, T, g, g + RG, NG);
  }
}

// Round 5
// 1013.422 us; speedup vs baseline: 1.4722x; 1.4722x over previous
//
#include <hip/hip_runtime.h>

typedef float f32x4 __attribute__((ext_vector_type(4)));
typedef __bf16 bf16x8 __attribute__((ext_vector_type(8)));
typedef unsigned short u16x8 __attribute__((ext_vector_type(8)));
typedef unsigned short u16x4 __attribute__((ext_vector_type(4)));

static __device__ __forceinline__ unsigned short f2bf(float f) {
  unsigned int x = __builtin_bit_cast(unsigned int, f);
  x += 0x7FFFu + ((x >> 16) & 1u);
  return (unsigned short)(x >> 16);
}
static __device__ __forceinline__ float bf2f(unsigned short h) {
  unsigned int x = ((unsigned int)h) << 16;
  return __builtin_bit_cast(float, x);
}

static __device__ __forceinline__ void gload_lds16(const unsigned short* g,
                                                   unsigned short* l) {
  __builtin_amdgcn_global_load_lds(
      (const __attribute__((address_space(1))) void*)g,
      (__attribute__((address_space(3))) void*)l, 16, 0, 0);
}

// ---------------- f32 -> bf16 elementwise (vectorized) ----------------
__global__ __launch_bounds__(256) void k_f32_to_bf16(
    const float* __restrict__ in, unsigned short* __restrict__ out, int n4) {
  int i = blockIdx.x * 256 + threadIdx.x;
  if (i >= n4) return;
  float4 v = reinterpret_cast<const float4*>(in)[i];
  u16x4 o = {f2bf(v.x), f2bf(v.y), f2bf(v.z), f2bf(v.w)};
  reinterpret_cast<u16x4*>(out)[i] = o;
}

// ------- transpose+convert into grouped B^T layout -------
// matrix z (768x768 f32, h@W convention) -> out_group[n][j*768+k] = W[k][n]
// where j = z%RG within group, group = z/RG; out row-length ld = RG*768.
__global__ __launch_bounds__(256) void k_transpose_w(
    const float* __restrict__ in, unsigned short* __restrict__ out, int RG) {
  __shared__ float tile[32][33];
  const int D = 768;
  int z = blockIdx.z;
  int j = z % RG, grp = z / RG;
  const float* A = in + (size_t)z * D * D;
  const size_t ld = (size_t)RG * D;
  unsigned short* O = out + (size_t)grp * D * ld + (size_t)j * D;
  int nt = blockIdx.x * 32, kt = blockIdx.y * 32;
  int tx = threadIdx.x, ty = threadIdx.y;
#pragma unroll
  for (int i = 0; i < 4; ++i)
    tile[ty + i * 8][tx] = A[(size_t)(kt + ty + i * 8) * D + nt + tx];
  __syncthreads();
#pragma unroll
  for (int i = 0; i < 4; ++i)
    O[(size_t)(nt + ty + i * 8) * ld + kt + tx] = f2bf(tile[tx][ty + i * 8]);
}

// ---------------- edge sort by (rel, dst) ----------------
__global__ __launch_bounds__(256) void k_hist(const int* __restrict__ dst,
                                              const int* __restrict__ rel,
                                              int* __restrict__ cnt, int E, int NV) {
  int e = blockIdx.x * 256 + threadIdx.x;
  if (e < E) atomicAdd(&cnt[rel[e] * NV + dst[e]], 1);
}

// hierarchical exclusive scan over n elements: part -> scan_b -> scan_f
__global__ __launch_bounds__(256) void k_part(const int* __restrict__ cnt,
                                              int* __restrict__ bsum, int n) {
  __shared__ int wsums[4];
  int blk = blockIdx.x, tid = threadIdx.x;
  int base = blk * 1024 + tid * 4;
  int s = 0;
#pragma unroll
  for (int j = 0; j < 4; ++j) {
    int i = base + j;
    if (i < n) s += cnt[i];
  }
#pragma unroll
  for (int d = 1; d < 64; d <<= 1) s += __shfl_xor(s, d, 64);
  if ((tid & 63) == 0) wsums[tid >> 6] = s;
  __syncthreads();
  if (tid == 0) bsum[blk] = wsums[0] + wsums[1] + wsums[2] + wsums[3];
}

__global__ __launch_bounds__(1024) void k_scan_b(const int* __restrict__ bsum,
                                                 int* __restrict__ bscan, int nb,
                                                 int* __restrict__ off_total) {
  __shared__ int wpre[16];
  int tid = threadIdx.x, lane = tid & 63, w = tid >> 6;
  int v = (tid < nb) ? bsum[tid] : 0;
  int inc = v;
#pragma unroll
  for (int d = 1; d < 64; d <<= 1) {
    int t = __shfl_up(inc, d, 64);
    if (lane >= d) inc += t;
  }
  if (lane == 63) wpre[w] = inc;
  __syncthreads();
  if (w == 0) {
    int vv = (lane < 16) ? wpre[lane] : 0;
    int p = vv;
#pragma unroll
    for (int d = 1; d < 16; d <<= 1) {
      int t = __shfl_up(p, d, 64);
      if (lane >= d) p += t;
    }
    if (lane < 16) wpre[lane] = p - vv;  // exclusive wave base
  }
  __syncthreads();
  if (tid < nb) bscan[tid] = wpre[w] + inc - v;
  if (tid == 1023) *off_total = wpre[15] + inc;  // grand total
}

__global__ __launch_bounds__(256) void k_scan_f(const int* __restrict__ cnt,
                                                const int* __restrict__ bscan,
                                                int* __restrict__ off, int n) {
  __shared__ int wpre[4];
  int blk = blockIdx.x, tid = threadIdx.x, lane = tid & 63, w = tid >> 6;
  int base = blk * 1024 + tid * 4;
  int v[4];
  int s = 0;
#pragma unroll
  for (int j = 0; j < 4; ++j) {
    int i = base + j;
    v[j] = (i < n) ? cnt[i] : 0;
    s += v[j];
  }
  int inc = s;
#pragma unroll
  for (int d = 1; d < 64; d <<= 1) {
    int t = __shfl_up(inc, d, 64);
    if (lane >= d) inc += t;
  }
  if (lane == 63) wpre[w] = inc;
  __syncthreads();
  int wb = 0;
  for (int j = 0; j < w; ++j) wb += wpre[j];
  int run = bscan[blk] + wb + (inc - s);
#pragma unroll
  for (int j = 0; j < 4; ++j) {
    int i = base + j;
    if (i < n) off[i] = run;
    run += v[j];
  }
}

__global__ __launch_bounds__(256) void k_bucket(
    const int* __restrict__ src, const int* __restrict__ dst,
    const int* __restrict__ rel, const float* __restrict__ norm,
    const int* __restrict__ off, int* __restrict__ fill,
    int* __restrict__ spack, float* __restrict__ snorm, int E, int NV) {
  int e = blockIdx.x * 256 + threadIdx.x;
  if (e >= E) return;
  int key = rel[e] * NV + dst[e];
  int slot = off[key] + atomicAdd(&fill[key], 1);
  spack[slot] = src[e];
  snorm[slot] = norm[e];
}

// ------- gather-aggregate into K-concat A slices: Acat[v][(r-r0)*768+c] -------
// A_r[v] = sum over in-edges (r,v) of norm * h[src]; h is L2/L3-resident.
// Wave per node; lane owns cols {lane*4 + c*256, c<3, +0..3}; zero-fills empties.
__global__ __launch_bounds__(256) void k_gather(
    const unsigned short* __restrict__ h, const int* __restrict__ off,
    const int* __restrict__ spack, const float* __restrict__ snorm,
    unsigned short* __restrict__ Acat, int NV, int r0, int r1, int ld) {
  int v = (blockIdx.x * 256 + threadIdx.x) >> 6;
  int lane = threadIdx.x & 63;
  int col = lane * 4;
  for (int r = r0; r < r1; ++r) {
    float a[12];
#pragma unroll
    for (int j = 0; j < 12; ++j) a[j] = 0.f;
    if (v < NV) {
      int beg = off[r * NV + v], end = off[r * NV + v + 1];
      for (int p = beg; p < end; ++p) {
        const unsigned short* row = h + (size_t)spack[p] * 768 + col;
        float nm = snorm[p];
#pragma unroll
        for (int c = 0; c < 3; ++c) {
          u16x4 vv = *reinterpret_cast<const u16x4*>(row + c * 256);
#pragma unroll
          for (int j = 0; j < 4; ++j) a[c * 4 + j] += nm * bf2f(vv[j]);
        }
      }
    }
    unsigned short* orow = Acat + (size_t)v * ld + (size_t)(r - r0) * 768 + col;
#pragma unroll
    for (int c = 0; c < 3; ++c) {
      u16x4 o = {f2bf(a[c * 4 + 0]), f2bf(a[c * 4 + 1]),
                 f2bf(a[c * 4 + 2]), f2bf(a[c * 4 + 3])};
      *reinterpret_cast<u16x4*>(orow + c * 256) = o;
    }
  }
}

// ---------------- bf16 GEMM: C[M,N] = A[M,K] @ B^T[N,K], f32 accum ----------------
// 256x256 tile, BK=64, 8 waves, 4-phase double-buffered schedule with counted
// vmcnt(4) (T4), setprio around MFMA clusters (T5), 16B-chunk XOR swizzle on
// pre-swizzled global source (T2). A rows padded to 256; B rows = N (mult 256).
// EPI: 0 = bf16 C; 1 = bf16 relu(acc + C0_f32); 2 = f32 C; 3 = f32 acc + C0.
#define STAGE_A(BUF, HALF, TT)                                                   \
  do {                                                                           \
    const unsigned short* _s =                                                   \
        A + (size_t)(m0 + (HALF) * 128 + srow) * K + (size_t)(TT) * 64 + gcol;   \
    gload_lds16(_s, &As[BUF][HALF][w << 3][0]);                                  \
    gload_lds16(_s + (size_t)64 * K, &As[BUF][HALF][64 + (w << 3)][0]);          \
  } while (0)
#define STAGE_B(BUF, HALF, TT)                                                   \
  do {                                                                           \
    const unsigned short* _s =                                                   \
        B + (size_t)(n0 + (HALF) * 128 + srow) * K + (size_t)(TT) * 64 + gcol;   \
    gload_lds16(_s, &Bs[BUF][HALF][w << 3][0]);                                  \
    gload_lds16(_s + (size_t)64 * K, &Bs[BUF][HALF][64 + (w << 3)][0]);          \
  } while (0)
#define PHASE(MA, NB, ...)                                                       \
  do {                                                                           \
    bf16x8 af[4][2], bv[2][2];                                                   \
    _Pragma("unroll") for (int i = 0; i < 4; ++i)                                \
        _Pragma("unroll") for (int kk = 0; kk < 2; ++kk)                         \
            af[i][kk] = *reinterpret_cast<const bf16x8*>(                        \
                &As[buf][MA][wr * 64 + i * 16 + lr]                              \
                   [((lg + 4 * kk) ^ (lr & 7)) * 8]);                            \
    _Pragma("unroll") for (int j = 0; j < 2; ++j)                                \
        _Pragma("unroll") for (int kk = 0; kk < 2; ++kk)                         \
            bv[j][kk] = *reinterpret_cast<const bf16x8*>(                        \
                &Bs[buf][NB][wc * 32 + j * 16 + lr]                              \
                   [((lg + 4 * kk) ^ (lr & 7)) * 8]);                            \
    __VA_ARGS__;                                                                 \
    asm volatile("" ::: "memory");                                               \
    __builtin_amdgcn_s_barrier();                                                \
    asm volatile("" ::: "memory");                                               \
    __builtin_amdgcn_s_setprio(1);                                               \
    _Pragma("unroll") for (int i = 0; i < 4; ++i)                                \
        _Pragma("unroll") for (int j = 0; j < 2; ++j)                            \
            _Pragma("unroll") for (int kk = 0; kk < 2; ++kk)                     \
                acc[MA][NB][i][j] = __builtin_amdgcn_mfma_f32_16x16x32_bf16(     \
                    af[i][kk], bv[j][kk], acc[MA][NB][i][j], 0, 0, 0);           \
    __builtin_amdgcn_s_setprio(0);                                               \
    asm volatile("" ::: "memory");                                               \
    __builtin_amdgcn_s_barrier();                                                \
    asm volatile("" ::: "memory");                                               \
  } while (0)

template <int EPI>
__global__ __launch_bounds__(512, 2) void k_gemm_tn(
    const unsigned short* __restrict__ A, const unsigned short* __restrict__ B,
    void* __restrict__ Cp, const float* __restrict__ C0,
    int M, int N, int K, int MT, int NT) {
  __shared__ unsigned short As[2][2][128][64];
  __shared__ unsigned short Bs[2][2][128][64];
  const int tid = threadIdx.x;
  const int lane = tid & 63;
  const int w = tid >> 6;
  const int wr = w >> 2;
  const int wc = w & 3;
  const int lr = lane & 15, lg = lane >> 4;

  int bid = blockIdx.x;
  const int per = 8 * NT;
  int grp = bid / per, rem = bid % per;
  int mstart = grp * 8;
  int gsz = MT - mstart; if (gsz > 8) gsz = 8;
  const int mt = mstart + rem % gsz;
  const int ntile = rem / gsz;
  const int m0 = mt * 256, n0 = ntile * 256;

  const int srow = tid >> 3;
  const int gcol = (((tid & 7) ^ (tid >> 3)) & 7) * 8;

  f32x4 acc[2][2][4][2] = {};
  const int nk = K >> 6;

  STAGE_A(0, 0, 0);
  STAGE_B(0, 1, 0);
  STAGE_A(0, 1, 0);
  STAGE_B(0, 0, 0);
  if (nk > 1) {
    STAGE_A(1, 0, 1);
    STAGE_B(1, 1, 1);
  }

  for (int t = 0; t < nk; ++t) {
    const int buf = t & 1;
    if (t + 1 < nk)
      asm volatile("s_waitcnt vmcnt(4)" ::: "memory");
    else
      asm volatile("s_waitcnt vmcnt(0)" ::: "memory");
    __builtin_amdgcn_s_barrier();
    asm volatile("" ::: "memory");
    PHASE(0, 1, if (t + 1 < nk) STAGE_A(buf ^ 1, 1, t + 1));
    PHASE(0, 0, if (t + 1 < nk) STAGE_B(buf ^ 1, 0, t + 1));
    PHASE(1, 1, if (t + 2 < nk) STAGE_A(buf, 0, t + 2));
    PHASE(1, 0, if (t + 2 < nk) STAGE_B(buf, 1, t + 2));
  }

#pragma unroll
  for (int ma = 0; ma < 2; ++ma)
#pragma unroll
    for (int i = 0; i < 4; ++i)
#pragma unroll
      for (int q = 0; q < 4; ++q) {
        int r = m0 + ma * 128 + wr * 64 + i * 16 + lg * 4 + q;
        if (r >= M) continue;
#pragma unroll
        for (int nb = 0; nb < 2; ++nb)
#pragma unroll
          for (int j = 0; j < 2; ++j) {
            int cn = n0 + nb * 128 + wc * 32 + j * 16 + lr;
            float v = acc[ma][nb][i][j][q];
            size_t idx = (size_t)r * N + cn;
            if (EPI == 0) {
              ((unsigned short*)Cp)[idx] = f2bf(v);
            } else if (EPI == 1) {
              v += C0[idx];
              v = v > 0.f ? v : 0.f;
              ((unsigned short*)Cp)[idx] = f2bf(v);
            } else if (EPI == 2) {
              ((float*)Cp)[idx] = v;
            } else {
              ((float*)Cp)[idx] = v + C0[idx];
            }
          }
      }
}

// ---------------- DistMult score: out[t] = dot(SW[es, er], emb[eo]) ----------------
__global__ __launch_bounds__(256) void k_score(
    const unsigned short* __restrict__ SW, const unsigned short* __restrict__ emb,
    const int* __restrict__ ps, const int* __restrict__ pr, const int* __restrict__ pd,
    const int* __restrict__ ns, const int* __restrict__ nr, const int* __restrict__ nd,
    float* __restrict__ out, int T, int r0, int r1, int ldSW) {
  int t = (blockIdx.x * 256 + threadIdx.x) >> 6;
  if (t >= 2 * T) return;
  int s, r, o;
  if (t < T) { s = ps[t]; r = pr[t]; o = pd[t]; }
  else       { s = ns[t - T]; r = nr[t - T]; o = nd[t - T]; }
  if (r < r0 || r >= r1) return;
  int lane = threadIdx.x & 63;
  int col = lane * 4;
  const unsigned short* a = SW + (size_t)s * ldSW + (size_t)(r - r0) * 768 + col;
  const unsigned short* b = emb + (size_t)o * 768 + col;
  float acc = 0.f;
#pragma unroll
  for (int c = 0; c < 3; ++c) {
    u16x4 va = *reinterpret_cast<const u16x4*>(a + c * 256);
    u16x4 vb = *reinterpret_cast<const u16x4*>(b + c * 256);
#pragma unroll
    for (int j = 0; j < 4; ++j) acc += bf2f(va[j]) * bf2f(vb[j]);
  }
#pragma unroll
  for (int off = 32; off > 0; off >>= 1) acc += __shfl_down(acc, off, 64);
  if (lane == 0) out[t] = acc;
}

extern "C" void kernel_launch(void* const* d_in, const int* in_sizes, int n_in,
                              void* d_out, int out_size, void* d_ws, size_t ws_size,
                              hipStream_t stream) {
  const float* node_feat = (const float*)d_in[0];
  const float* edge_norm = (const float*)d_in[1];
  const float* W_rel = (const float*)d_in[2];
  const float* W_self = (const float*)d_in[3];
  const float* w_relation = (const float*)d_in[4];
  const int* src = (const int*)d_in[5];
  const int* dst = (const int*)d_in[6];
  const int* rel = (const int*)d_in[7];
  const int* pos_src = (const int*)d_in[8];
  const int* pos_rel = (const int*)d_in[9];
  const int* pos_dst = (const int*)d_in[10];
  const int* neg_src = (const int*)d_in[11];
  const int* neg_rel = (const int*)d_in[12];
  const int* neg_dst = (const int*)d_in[13];

  const int D = 768;
  const int NV = in_sizes[0] / D;
  const int E = in_sizes[1];
  const int L = in_sizes[3] / (D * D);
  const int R = in_sizes[4] / (D * D);
  const int T = in_sizes[8];
  const int Mpad = (NV + 255) & ~255;
  const int RN = R * NV;
  const int NB = (RN + 1023) / 1024;

  auto align_up = [](size_t x) { return (x + 255) & ~(size_t)255; };
  size_t sz_wt_rel = align_up((size_t)L * R * D * D * 2);
  size_t sz_wt_self = align_up((size_t)L * D * D * 2);
  size_t sz_wt_score = align_up((size_t)R * D * D * 2);
  size_t sz_h = align_up((size_t)Mpad * D * 2);
  size_t sz_agg = align_up((size_t)Mpad * D * 4);
  size_t sz_cntfill = align_up((size_t)2 * RN * 4);
  size_t sz_off = align_up((size_t)(RN + 8) * 4);
  size_t sz_sp = align_up((size_t)E * 4);
  size_t sz_bs = align_up((size_t)2 * (NB + 8) * 4);
  size_t fixed = sz_wt_rel + sz_wt_self + sz_wt_score + sz_h + sz_agg +
                 sz_cntfill + sz_off + 2 * sz_sp + sz_bs;
  int RG = 4;
  while (RG > 1 && fixed + align_up((size_t)Mpad * RG * D * 2) > ws_size) RG >>= 1;
  const int NGRP = R / RG;

  char* wp = (char*)d_ws;
  unsigned short* wt_rel = (unsigned short*)wp; wp += sz_wt_rel;   // [l,g][768][RG*768]
  unsigned short* wt_self = (unsigned short*)wp; wp += sz_wt_self; // [l][768][768]
  unsigned short* wt_score = (unsigned short*)wp; wp += sz_wt_score; // [r*768][768]
  unsigned short* h = (unsigned short*)wp; wp += sz_h;
  float* agg = (float*)wp; wp += sz_agg;
  int* cnt = (int*)wp; int* fill = cnt + RN; wp += sz_cntfill;
  int* off = (int*)wp; wp += sz_off;
  int* spack = (int*)wp; wp += sz_sp;
  float* snorm = (float*)wp; wp += sz_sp;
  int* bsum = (int*)wp; int* bscan = bsum + NB + 4; wp += sz_bs;
  unsigned short* Acat = (unsigned short*)wp;  // [Mpad][RG*768], also SW buffer

  dim3 tb32(32, 8);
  // h = bf16(node_feat), zero pad rows
  k_f32_to_bf16<<<(NV * D / 4 + 255) / 256, 256, 0, stream>>>(node_feat, h, NV * D / 4);
  if (Mpad > NV)
    hipMemsetAsync(h + (size_t)NV * D, 0, (size_t)(Mpad - NV) * D * 2, stream);
  // weights: grouped B^T layouts
  k_transpose_w<<<dim3(24, 24, L * R), tb32, 0, stream>>>(W_rel, wt_rel, RG);
  k_transpose_w<<<dim3(24, 24, L), tb32, 0, stream>>>(W_self, wt_self, 1);
  k_transpose_w<<<dim3(24, 24, R), tb32, 0, stream>>>(w_relation, wt_score, 1);

  // counting sort of edges by (rel, dst) with hierarchical scan
  hipMemsetAsync(cnt, 0, (size_t)2 * RN * 4, stream);
  k_hist<<<(E + 255) / 256, 256, 0, stream>>>(dst, rel, cnt, E, NV);
  k_part<<<NB, 256, 0, stream>>>(cnt, bsum, RN);
  k_scan_b<<<1, 1024, 0, stream>>>(bsum, bscan, NB, off + RN);
  k_scan_f<<<NB, 256, 0, stream>>>(cnt, bscan, off, RN);
  k_bucket<<<(E + 255) / 256, 256, 0, stream>>>(src, dst, rel, edge_norm, off, fill,
                                                spack, snorm, E, NV);

  const int MT = Mpad / 256;
  const int KG = RG * D;
  const int gblocks = Mpad / 4;
  for (int l = 0; l < L; ++l) {
    // agg = h @ W_self[l]
    k_gemm_tn<2><<<MT * 3, 512, 0, stream>>>(
        h, wt_self + (size_t)l * D * D, agg, nullptr, NV, D, D, MT, 3);
    for (int gi = 0; gi < NGRP; ++gi) {
      k_gather<<<gblocks, 256, 0, stream>>>(h, off, spack, snorm, Acat, NV,
                                            gi * RG, gi * RG + RG, KG);
      const unsigned short* Bw = wt_rel + (size_t)(l * NGRP + gi) * D * KG;
      if (gi == NGRP - 1)  // last: h = relu(acc + agg), in place
        k_gemm_tn<1><<<MT * 3, 512, 0, stream>>>(Acat, Bw, h, agg, NV, D, KG, MT, 3);
      else
        k_gemm_tn<3><<<MT * 3, 512, 0, stream>>>(Acat, Bw, agg, agg, NV, D, KG, MT, 3);
    }
  }
  // scoring: per group, SW = h @ w_relation[group] (into Acat), then dot
  for (int gi = 0; gi < NGRP; ++gi) {
    k_gemm_tn<0><<<MT * RG * 3, 512, 0, stream>>>(
        h, wt_score + (size_t)gi * RG * D * D, Acat, nullptr, NV, KG, D, MT, RG * 3);
    k_score<<<(2 * T + 3) / 4, 256, 0, stream>>>(Acat, h, pos_src, pos_rel, pos_dst,
                                                 neg_src, neg_rel, neg_dst,
                                                 (float*)d_out, T, gi * RG,
                                                 gi * RG + RG, KG);
  }
}

// Round 6
// 883.245 us; speedup vs baseline: 1.6892x; 1.1474x over previous
//
#include <hip/hip_runtime.h>

typedef float f32x4 __attribute__((ext_vector_type(4)));
typedef __bf16 bf16x8 __attribute__((ext_vector_type(8)));
typedef unsigned short u16x8 __attribute__((ext_vector_type(8)));
typedef unsigned short u16x4 __attribute__((ext_vector_type(4)));

static __device__ __forceinline__ unsigned short f2bf(float f) {
  unsigned int x = __builtin_bit_cast(unsigned int, f);
  x += 0x7FFFu + ((x >> 16) & 1u);
  return (unsigned short)(x >> 16);
}
static __device__ __forceinline__ float bf2f(unsigned short h) {
  unsigned int x = ((unsigned int)h) << 16;
  return __builtin_bit_cast(float, x);
}

static __device__ __forceinline__ void gload_lds16(const unsigned short* g,
                                                   unsigned short* l) {
  __builtin_amdgcn_global_load_lds(
      (const __attribute__((address_space(1))) void*)g,
      (__attribute__((address_space(3))) void*)l, 16, 0, 0);
}

// ---------------- f32 -> bf16 elementwise (vectorized) ----------------
__global__ __launch_bounds__(256) void k_f32_to_bf16(
    const float* __restrict__ in, unsigned short* __restrict__ out, int n4) {
  int i = blockIdx.x * 256 + threadIdx.x;
  if (i >= n4) return;
  float4 v = reinterpret_cast<const float4*>(in)[i];
  u16x4 o = {f2bf(v.x), f2bf(v.y), f2bf(v.z), f2bf(v.w)};
  reinterpret_cast<u16x4*>(out)[i] = o;
}

// ------- transpose+convert into grouped B^T layout -------
// matrix z (768x768 f32, h@W convention) -> out_group[n][j*768+k] = W[k][n]
// where j = z%RG within group, group = z/RG; out row-length ld = RG*768.
__global__ __launch_bounds__(256) void k_transpose_w(
    const float* __restrict__ in, unsigned short* __restrict__ out, int RG) {
  __shared__ float tile[32][33];
  const int D = 768;
  int z = blockIdx.z;
  int j = z % RG, grp = z / RG;
  const float* A = in + (size_t)z * D * D;
  const size_t ld = (size_t)RG * D;
  unsigned short* O = out + (size_t)grp * D * ld + (size_t)j * D;
  int nt = blockIdx.x * 32, kt = blockIdx.y * 32;
  int tx = threadIdx.x, ty = threadIdx.y;
#pragma unroll
  for (int i = 0; i < 4; ++i)
    tile[ty + i * 8][tx] = A[(size_t)(kt + ty + i * 8) * D + nt + tx];
  __syncthreads();
#pragma unroll
  for (int i = 0; i < 4; ++i)
    O[(size_t)(nt + ty + i * 8) * ld + kt + tx] = f2bf(tile[tx][ty + i * 8]);
}

// ---------------- edge sort by (rel, dst) ----------------
__global__ __launch_bounds__(256) void k_hist(const int* __restrict__ dst,
                                              const int* __restrict__ rel,
                                              int* __restrict__ cnt, int E, int NV) {
  int e = blockIdx.x * 256 + threadIdx.x;
  if (e < E) atomicAdd(&cnt[rel[e] * NV + dst[e]], 1);
}

// hierarchical exclusive scan over n elements: part -> scan_b -> scan_f
__global__ __launch_bounds__(256) void k_part(const int* __restrict__ cnt,
                                              int* __restrict__ bsum, int n) {
  __shared__ int wsums[4];
  int blk = blockIdx.x, tid = threadIdx.x;
  int base = blk * 1024 + tid * 4;
  int s = 0;
#pragma unroll
  for (int j = 0; j < 4; ++j) {
    int i = base + j;
    if (i < n) s += cnt[i];
  }
#pragma unroll
  for (int d = 1; d < 64; d <<= 1) s += __shfl_xor(s, d, 64);
  if ((tid & 63) == 0) wsums[tid >> 6] = s;
  __syncthreads();
  if (tid == 0) bsum[blk] = wsums[0] + wsums[1] + wsums[2] + wsums[3];
}

__global__ __launch_bounds__(1024) void k_scan_b(const int* __restrict__ bsum,
                                                 int* __restrict__ bscan, int nb,
                                                 int* __restrict__ off_total) {
  __shared__ int wpre[16];
  int tid = threadIdx.x, lane = tid & 63, w = tid >> 6;
  int v = (tid < nb) ? bsum[tid] : 0;
  int inc = v;
#pragma unroll
  for (int d = 1; d < 64; d <<= 1) {
    int t = __shfl_up(inc, d, 64);
    if (lane >= d) inc += t;
  }
  if (lane == 63) wpre[w] = inc;
  __syncthreads();
  if (w == 0) {
    int vv = (lane < 16) ? wpre[lane] : 0;
    int p = vv;
#pragma unroll
    for (int d = 1; d < 16; d <<= 1) {
      int t = __shfl_up(p, d, 64);
      if (lane >= d) p += t;
    }
    if (lane < 16) wpre[lane] = p - vv;  // exclusive wave base
  }
  __syncthreads();
  if (tid < nb) bscan[tid] = wpre[w] + inc - v;
  if (tid == 1023) *off_total = wpre[15] + inc;  // grand total
}

__global__ __launch_bounds__(256) void k_scan_f(const int* __restrict__ cnt,
                                                const int* __restrict__ bscan,
                                                int* __restrict__ off, int n) {
  __shared__ int wpre[4];
  int blk = blockIdx.x, tid = threadIdx.x, lane = tid & 63, w = tid >> 6;
  int base = blk * 1024 + tid * 4;
  int v[4];
  int s = 0;
#pragma unroll
  for (int j = 0; j < 4; ++j) {
    int i = base + j;
    v[j] = (i < n) ? cnt[i] : 0;
    s += v[j];
  }
  int inc = s;
#pragma unroll
  for (int d = 1; d < 64; d <<= 1) {
    int t = __shfl_up(inc, d, 64);
    if (lane >= d) inc += t;
  }
  if (lane == 63) wpre[w] = inc;
  __syncthreads();
  int wb = 0;
  for (int j = 0; j < w; ++j) wb += wpre[j];
  int run = bscan[blk] + wb + (inc - s);
#pragma unroll
  for (int j = 0; j < 4; ++j) {
    int i = base + j;
    if (i < n) off[i] = run;
    run += v[j];
  }
}

__global__ __launch_bounds__(256) void k_bucket(
    const int* __restrict__ src, const int* __restrict__ dst,
    const int* __restrict__ rel, const float* __restrict__ norm,
    const int* __restrict__ off, int* __restrict__ fill,
    int* __restrict__ spack, float* __restrict__ snorm, int E, int NV) {
  int e = blockIdx.x * 256 + threadIdx.x;
  if (e >= E) return;
  int key = rel[e] * NV + dst[e];
  int slot = off[key] + atomicAdd(&fill[key], 1);
  spack[slot] = src[e];
  snorm[slot] = norm[e];
}

// ------- gather-aggregate into K-concat A slices: Acat[v][(r-r0)*768+c] -------
// A_r[v] = sum over in-edges (r,v) of norm * h[src]; h is L2/L3-resident.
__global__ __launch_bounds__(256) void k_gather(
    const unsigned short* __restrict__ h, const int* __restrict__ off,
    const int* __restrict__ spack, const float* __restrict__ snorm,
    unsigned short* __restrict__ Acat, int NV, int r0, int r1, int ld) {
  int v = (blockIdx.x * 256 + threadIdx.x) >> 6;
  int lane = threadIdx.x & 63;
  int col = lane * 4;
  for (int r = r0; r < r1; ++r) {
    float a[12];
#pragma unroll
    for (int j = 0; j < 12; ++j) a[j] = 0.f;
    if (v < NV) {
      int beg = off[r * NV + v], end = off[r * NV + v + 1];
      for (int p = beg; p < end; ++p) {
        const unsigned short* row = h + (size_t)spack[p] * 768 + col;
        float nm = snorm[p];
#pragma unroll
        for (int c = 0; c < 3; ++c) {
          u16x4 vv = *reinterpret_cast<const u16x4*>(row + c * 256);
#pragma unroll
          for (int j = 0; j < 4; ++j) a[c * 4 + j] += nm * bf2f(vv[j]);
        }
      }
    }
    unsigned short* orow = Acat + (size_t)v * ld + (size_t)(r - r0) * 768 + col;
#pragma unroll
    for (int c = 0; c < 3; ++c) {
      u16x4 o = {f2bf(a[c * 4 + 0]), f2bf(a[c * 4 + 1]),
                 f2bf(a[c * 4 + 2]), f2bf(a[c * 4 + 3])};
      *reinterpret_cast<u16x4*>(orow + c * 256) = o;
    }
  }
}

// ---------------- bf16 GEMM: C[M,N] = A[M,K] @ B^T[N,K], f32 accum ----------------
// 256x256 tile, BK=64, 8 waves (wave output 128x64). 2-phase K-tile schedule:
//   Phase A (ma=0): 16 ds_read_b128 (A-half0 + BOTH B-halves), stage t+1.Ahi/Blo
//                   into buf^1, 32 MFMA.
//   Phase B (ma=1): 8 ds_read (A-half1), REUSE bv from registers, stage
//                   t+2.Alo/Bhi into buf (all reads of those regions completed
//                   in phase A, enforced by the mid-tile barrier), 32 MFMA.
// 24 ds_read / 64 MFMA / 2 barriers per K-tile (LDS no longer the phase
// critical path). Counted vmcnt(4): per tile, 4 loads of t+1 issued last tile
// + 4 of t+2 this tile; vmcnt(4) at tile t+1 retires exactly all of t+1 (T4).
// 16B-chunk XOR swizzle chunk^=(row&7) on pre-swizzled global source (T2);
// setprio around MFMA clusters (T5). A/B rows padded to multiples of 256.
// EPI: 0 = bf16 C; 1 = bf16 relu(acc + C0_f32); 2 = f32 C; 3 = f32 acc + C0.
#define STAGE_A(BUF, HALF, TT)                                                   \
  do {                                                                           \
    const unsigned short* _s =                                                   \
        A + (size_t)(m0 + (HALF) * 128 + srow) * K + (size_t)(TT) * 64 + gcol;   \
    gload_lds16(_s, &As[BUF][HALF][w << 3][0]);                                  \
    gload_lds16(_s + (size_t)64 * K, &As[BUF][HALF][64 + (w << 3)][0]);          \
  } while (0)
#define STAGE_B(BUF, HALF, TT)                                                   \
  do {                                                                           \
    const unsigned short* _s =                                                   \
        B + (size_t)(n0 + (HALF) * 128 + srow) * K + (size_t)(TT) * 64 + gcol;   \
    gload_lds16(_s, &Bs[BUF][HALF][w << 3][0]);                                  \
    gload_lds16(_s + (size_t)64 * K, &Bs[BUF][HALF][64 + (w << 3)][0]);          \
  } while (0)

template <int EPI>
__global__ __launch_bounds__(512, 2) void k_gemm_tn(
    const unsigned short* __restrict__ A, const unsigned short* __restrict__ B,
    void* __restrict__ Cp, const float* __restrict__ C0,
    int M, int N, int K, int MT, int NT) {
  __shared__ unsigned short As[2][2][128][64];
  __shared__ unsigned short Bs[2][2][128][64];
  const int tid = threadIdx.x;
  const int lane = tid & 63;
  const int w = tid >> 6;
  const int wr = w >> 2;   // 0..1
  const int wc = w & 3;    // 0..3
  const int lr = lane & 15, lg = lane >> 4;

  int bid = blockIdx.x;
  const int per = 8 * NT;
  int grp = bid / per, rem = bid % per;
  int mstart = grp * 8;
  int gsz = MT - mstart; if (gsz > 8) gsz = 8;
  const int mt = mstart + rem % gsz;
  const int ntile = rem / gsz;
  const int m0 = mt * 256, n0 = ntile * 256;

  const int srow = tid >> 3;
  const int gcol = (((tid & 7) ^ (tid >> 3)) & 7) * 8;

  f32x4 acc[2][2][4][2] = {};  // [ma][nb][i][j]
  const int nk = K >> 6;

  // prologue: t0 all 4 halves -> buf0; t1.Alo + t1.Bhi -> buf1
  STAGE_A(0, 0, 0);
  STAGE_B(0, 1, 0);
  STAGE_A(0, 1, 0);
  STAGE_B(0, 0, 0);
  if (nk > 1) {
    STAGE_A(1, 0, 1);
    STAGE_B(1, 1, 1);
  }

  bf16x8 af[4][2], bv[2][2][2];
  for (int t = 0; t < nk; ++t) {
    const int buf = t & 1;
    if (t + 1 < nk)
      asm volatile("s_waitcnt vmcnt(4)" ::: "memory");
    else
      asm volatile("s_waitcnt vmcnt(0)" ::: "memory");
    __builtin_amdgcn_s_barrier();
    asm volatile("" ::: "memory");
    // ---- Phase A: ma = 0; read A-half0 + both B-halves ----
#pragma unroll
    for (int i = 0; i < 4; ++i)
#pragma unroll
      for (int kk = 0; kk < 2; ++kk)
        af[i][kk] = *reinterpret_cast<const bf16x8*>(
            &As[buf][0][wr * 64 + i * 16 + lr][((lg + 4 * kk) ^ (lr & 7)) * 8]);
#pragma unroll
    for (int nb = 0; nb < 2; ++nb)
#pragma unroll
      for (int j = 0; j < 2; ++j)
#pragma unroll
        for (int kk = 0; kk < 2; ++kk)
          bv[nb][j][kk] = *reinterpret_cast<const bf16x8*>(
              &Bs[buf][nb][wc * 32 + j * 16 + lr][((lg + 4 * kk) ^ (lr & 7)) * 8]);
    if (t + 1 < nk) {
      STAGE_A(buf ^ 1, 1, t + 1);
      STAGE_B(buf ^ 1, 0, t + 1);
    }
    __builtin_amdgcn_s_setprio(1);
#pragma unroll
    for (int i = 0; i < 4; ++i)
#pragma unroll
      for (int nb = 0; nb < 2; ++nb)
#pragma unroll
        for (int j = 0; j < 2; ++j)
#pragma unroll
          for (int kk = 0; kk < 2; ++kk)
            acc[0][nb][i][j] = __builtin_amdgcn_mfma_f32_16x16x32_bf16(
                af[i][kk], bv[nb][j][kk], acc[0][nb][i][j], 0, 0, 0);
    __builtin_amdgcn_s_setprio(0);
    asm volatile("" ::: "memory");
    __builtin_amdgcn_s_barrier();  // all phase-A reads of As[buf][0]/Bs[buf][*] done
    asm volatile("" ::: "memory");
    // ---- Phase B: ma = 1; read A-half1, reuse bv ----
#pragma unroll
    for (int i = 0; i < 4; ++i)
#pragma unroll
      for (int kk = 0; kk < 2; ++kk)
        af[i][kk] = *reinterpret_cast<const bf16x8*>(
            &As[buf][1][wr * 64 + i * 16 + lr][((lg + 4 * kk) ^ (lr & 7)) * 8]);
    if (t + 2 < nk) {
      STAGE_A(buf, 0, t + 2);
      STAGE_B(buf, 1, t + 2);
    }
    __builtin_amdgcn_s_setprio(1);
#pragma unroll
    for (int i = 0; i < 4; ++i)
#pragma unroll
      for (int nb = 0; nb < 2; ++nb)
#pragma unroll
        for (int j = 0; j < 2; ++j)
#pragma unroll
          for (int kk = 0; kk < 2; ++kk)
            acc[1][nb][i][j] = __builtin_amdgcn_mfma_f32_16x16x32_bf16(
                af[i][kk], bv[nb][j][kk], acc[1][nb][i][j], 0, 0, 0);
    __builtin_amdgcn_s_setprio(0);
  }

#pragma unroll
  for (int ma = 0; ma < 2; ++ma)
#pragma unroll
    for (int i = 0; i < 4; ++i)
#pragma unroll
      for (int q = 0; q < 4; ++q) {
        int r = m0 + ma * 128 + wr * 64 + i * 16 + lg * 4 + q;
        if (r >= M) continue;
#pragma unroll
        for (int nb = 0; nb < 2; ++nb)
#pragma unroll
          for (int j = 0; j < 2; ++j) {
            int cn = n0 + nb * 128 + wc * 32 + j * 16 + lr;
            float v = acc[ma][nb][i][j][q];
            size_t idx = (size_t)r * N + cn;
            if (EPI == 0) {
              ((unsigned short*)Cp)[idx] = f2bf(v);
            } else if (EPI == 1) {
              v += C0[idx];
              v = v > 0.f ? v : 0.f;
              ((unsigned short*)Cp)[idx] = f2bf(v);
            } else if (EPI == 2) {
              ((float*)Cp)[idx] = v;
            } else {
              ((float*)Cp)[idx] = v + C0[idx];
            }
          }
      }
}

// ---------------- DistMult score: out[t] = dot(SW[es, er], emb[eo]) ----------------
__global__ __launch_bounds__(256) void k_score(
    const unsigned short* __restrict__ SW, const unsigned short* __restrict__ emb,
    const int* __restrict__ ps, const int* __restrict__ pr, const int* __restrict__ pd,
    const int* __restrict__ ns, const int* __restrict__ nr, const int* __restrict__ nd,
    float* __restrict__ out, int T, int r0, int r1, int ldSW) {
  int t = (blockIdx.x * 256 + threadIdx.x) >> 6;
  if (t >= 2 * T) return;
  int s, r, o;
  if (t < T) { s = ps[t]; r = pr[t]; o = pd[t]; }
  else       { s = ns[t - T]; r = nr[t - T]; o = nd[t - T]; }
  if (r < r0 || r >= r1) return;
  int lane = threadIdx.x & 63;
  int col = lane * 4;
  const unsigned short* a = SW + (size_t)s * ldSW + (size_t)(r - r0) * 768 + col;
  const unsigned short* b = emb + (size_t)o * 768 + col;
  float acc = 0.f;
#pragma unroll
  for (int c = 0; c < 3; ++c) {
    u16x4 va = *reinterpret_cast<const u16x4*>(a + c * 256);
    u16x4 vb = *reinterpret_cast<const u16x4*>(b + c * 256);
#pragma unroll
    for (int j = 0; j < 4; ++j) acc += bf2f(va[j]) * bf2f(vb[j]);
  }
#pragma unroll
  for (int off = 32; off > 0; off >>= 1) acc += __shfl_down(acc, off, 64);
  if (lane == 0) out[t] = acc;
}

extern "C" void kernel_launch(void* const* d_in, const int* in_sizes, int n_in,
                              void* d_out, int out_size, void* d_ws, size_t ws_size,
                              hipStream_t stream) {
  const float* node_feat = (const float*)d_in[0];
  const float* edge_norm = (const float*)d_in[1];
  const float* W_rel = (const float*)d_in[2];
  const float* W_self = (const float*)d_in[3];
  const float* w_relation = (const float*)d_in[4];
  const int* src = (const int*)d_in[5];
  const int* dst = (const int*)d_in[6];
  const int* rel = (const int*)d_in[7];
  const int* pos_src = (const int*)d_in[8];
  const int* pos_rel = (const int*)d_in[9];
  const int* pos_dst = (const int*)d_in[10];
  const int* neg_src = (const int*)d_in[11];
  const int* neg_rel = (const int*)d_in[12];
  const int* neg_dst = (const int*)d_in[13];

  const int D = 768;
  const int NV = in_sizes[0] / D;
  const int E = in_sizes[1];
  const int L = in_sizes[3] / (D * D);
  const int R = in_sizes[4] / (D * D);
  const int T = in_sizes[8];
  const int Mpad = (NV + 255) & ~255;
  const int RN = R * NV;
  const int NB = (RN + 1023) / 1024;

  auto align_up = [](size_t x) { return (x + 255) & ~(size_t)255; };
  size_t sz_wt_rel = align_up((size_t)L * R * D * D * 2);
  size_t sz_wt_self = align_up((size_t)L * D * D * 2);
  size_t sz_wt_score = align_up((size_t)R * D * D * 2);
  size_t sz_h = align_up((size_t)Mpad * D * 2);
  size_t sz_agg = align_up((size_t)Mpad * D * 4);
  size_t sz_cntfill = align_up((size_t)2 * RN * 4);
  size_t sz_off = align_up((size_t)(RN + 8) * 4);
  size_t sz_sp = align_up((size_t)E * 4);
  size_t sz_bs = align_up((size_t)2 * (NB + 8) * 4);
  size_t fixed = sz_wt_rel + sz_wt_self + sz_wt_score + sz_h + sz_agg +
                 sz_cntfill + sz_off + 2 * sz_sp + sz_bs;
  int RG = 4;
  while (RG > 1 && fixed + align_up((size_t)Mpad * RG * D * 2) > ws_size) RG >>= 1;
  const int NGRP = R / RG;

  char* wp = (char*)d_ws;
  unsigned short* wt_rel = (unsigned short*)wp; wp += sz_wt_rel;   // [l,g][768][RG*768]
  unsigned short* wt_self = (unsigned short*)wp; wp += sz_wt_self; // [l][768][768]
  unsigned short* wt_score = (unsigned short*)wp; wp += sz_wt_score; // [r*768][768]
  unsigned short* h = (unsigned short*)wp; wp += sz_h;
  float* agg = (float*)wp; wp += sz_agg;
  int* cnt = (int*)wp; int* fill = cnt + RN; wp += sz_cntfill;
  int* off = (int*)wp; wp += sz_off;
  int* spack = (int*)wp; wp += sz_sp;
  float* snorm = (float*)wp; wp += sz_sp;
  int* bsum = (int*)wp; int* bscan = bsum + NB + 4; wp += sz_bs;
  unsigned short* Acat = (unsigned short*)wp;  // [Mpad][RG*768], also SW buffer

  dim3 tb32(32, 8);
  // h = bf16(node_feat), zero pad rows
  k_f32_to_bf16<<<(NV * D / 4 + 255) / 256, 256, 0, stream>>>(node_feat, h, NV * D / 4);
  if (Mpad > NV)
    hipMemsetAsync(h + (size_t)NV * D, 0, (size_t)(Mpad - NV) * D * 2, stream);
  // weights: grouped B^T layouts
  k_transpose_w<<<dim3(24, 24, L * R), tb32, 0, stream>>>(W_rel, wt_rel, RG);
  k_transpose_w<<<dim3(24, 24, L), tb32, 0, stream>>>(W_self, wt_self, 1);
  k_transpose_w<<<dim3(24, 24, R), tb32, 0, stream>>>(w_relation, wt_score, 1);

  // counting sort of edges by (rel, dst) with hierarchical scan
  hipMemsetAsync(cnt, 0, (size_t)2 * RN * 4, stream);
  k_hist<<<(E + 255) / 256, 256, 0, stream>>>(dst, rel, cnt, E, NV);
  k_part<<<NB, 256, 0, stream>>>(cnt, bsum, RN);
  k_scan_b<<<1, 1024, 0, stream>>>(bsum, bscan, NB, off + RN);
  k_scan_f<<<NB, 256, 0, stream>>>(cnt, bscan, off, RN);
  k_bucket<<<(E + 255) / 256, 256, 0, stream>>>(src, dst, rel, edge_norm, off, fill,
                                                spack, snorm, E, NV);

  const int MT = Mpad / 256;
  const int KG = RG * D;
  const int gblocks = Mpad / 4;
  for (int l = 0; l < L; ++l) {
    // agg = h @ W_self[l]
    k_gemm_tn<2><<<MT * 3, 512, 0, stream>>>(
        h, wt_self + (size_t)l * D * D, agg, nullptr, NV, D, D, MT, 3);
    for (int gi = 0; gi < NGRP; ++gi) {
      k_gather<<<gblocks, 256, 0, stream>>>(h, off, spack, snorm, Acat, NV,
                                            gi * RG, gi * RG + RG, KG);
      const unsigned short* Bw = wt_rel + (size_t)(l * NGRP + gi) * D * KG;
      if (gi == NGRP - 1)  // last: h = relu(acc + agg), in place
        k_gemm_tn<1><<<MT * 3, 512, 0, stream>>>(Acat, Bw, h, agg, NV, D, KG, MT, 3);
      else
        k_gemm_tn<3><<<MT * 3, 512, 0, stream>>>(Acat, Bw, agg, agg, NV, D, KG, MT, 3);
    }
  }
  // scoring: per group, SW = h @ w_relation[group] (into Acat), then dot
  for (int gi = 0; gi < NGRP; ++gi) {
    k_gemm_tn<0><<<MT * RG * 3, 512, 0, stream>>>(
        h, wt_score + (size_t)gi * RG * D * D, Acat, nullptr, NV, KG, D, MT, RG * 3);
    k_score<<<(2 * T + 3) / 4, 256, 0, stream>>>(Acat, h, pos_src, pos_rel, pos_dst,
                                                 neg_src, neg_rel, neg_dst,
                                                 (float*)d_out, T, gi * RG,
                                                 gi * RG + RG, KG);
  }
}